// Round 8
// baseline (539.096 us; speedup 1.0000x reference)
//
#include <hip/hip_runtime.h>
#include <hip/hip_bf16.h>

#define DD 1024
#define HH 4096
#define EE 8
#define NN 4096   // B*T tokens

typedef __attribute__((ext_vector_type(8))) short bf16x8;
typedef __attribute__((ext_vector_type(4))) float f32x4;
typedef __attribute__((ext_vector_type(8))) unsigned short u16x8;

#define AS1P(p) ((__attribute__((address_space(1))) void*)(unsigned long long)(const void*)(p))
#define AS3P(p) ((__attribute__((address_space(3))) void*)(unsigned int)(unsigned long long)(const void*)(p))

__device__ inline f32x4 mfma16(bf16x8 a, bf16x8 b, f32x4 c) {
    return __builtin_amdgcn_mfma_f32_16x16x32_bf16(a, b, c, 0, 0, 0);
}

// ---------------------------------------------------------------------------
// Fused transpose + fp32->bf16 for W1, W2 (eg-scaled, eb@W bias) and Wo.
// z = 0..7: W1, 8..15: W2, 16..23: Wo.  tile pad 66: read stride 528%32=16 ->
// 2-way bank alias (free, m136); was 4-way at pad 65.
// ---------------------------------------------------------------------------
__global__ __launch_bounds__(256) void transpose_all(
    const float* __restrict__ W1, const float* __restrict__ W2,
    const float* __restrict__ Wo, const float* __restrict__ eg,
    const float* __restrict__ eb, __hip_bfloat16* __restrict__ W1T,
    __hip_bfloat16* __restrict__ W2T, __hip_bfloat16* __restrict__ WoT,
    float* __restrict__ b1a, float* __restrict__ b2a)
{
    __shared__ float tile[64][66];
    __shared__ float sg[64], sb[64];
    const int z   = blockIdx.z;
    const int mat = z >> 3;          // 0:W1 1:W2 2:Wo
    const int e   = z & 7;
    const int R   = (mat == 2) ? HH : DD;
    const int C   = (mat == 2) ? DD : HH;
    const int cT  = C >> 6;
    const int bx  = blockIdx.x;      // 0..1023
    const int c0  = (bx % cT) * 64;
    const int r0  = (bx / cT) * 64;
    const float* src = (mat == 0) ? W1 : (mat == 1) ? W2 : Wo;
    __hip_bfloat16* dst = (mat == 0) ? W1T : (mat == 1) ? W2T : WoT;
    const bool SC = (mat < 2);
    float* badd = (mat == 0) ? b1a : b2a;
    const int t = threadIdx.x;

    const float* s = src + (size_t)e * R * C + (size_t)r0 * C + c0;
    if (SC && t < 64) {
        sg[t] = eg[e * DD + r0 + t];
        sb[t] = eb[e * DD + r0 + t];
    }
    #pragma unroll
    for (int i = 0; i < 4; i++) {
        const int rr = i * 16 + (t >> 4);
        const int cc = (t & 15) * 4;
        const float4 v = *(const float4*)(s + (size_t)rr * C + cc);
        tile[rr][cc] = v.x; tile[rr][cc + 1] = v.y;
        tile[rr][cc + 2] = v.z; tile[rr][cc + 3] = v.w;
    }
    __syncthreads();

    __hip_bfloat16* d = dst + (size_t)e * R * C + (size_t)c0 * R + r0;
    #pragma unroll
    for (int i = 0; i < 2; i++) {
        const int id = t + 256 * i;
        const int cc = id >> 3;
        const int rb = (id & 7) * 8;
        union { u16x8 v; __hip_bfloat16 h[8]; } u;
        #pragma unroll
        for (int j = 0; j < 8; j++) {
            float v = tile[rb + j][cc];
            if (SC) v *= sg[rb + j];
            u.h[j] = __float2bfloat16(v);
        }
        *(u16x8*)(d + (size_t)cc * R + rb) = u.v;
    }
    if (SC && t < 64) {
        float sum = 0.f;
        #pragma unroll
        for (int rr = 0; rr < 64; rr++) sum += sb[rr] * tile[rr][t];
        atomicAdd(&badd[e * C + c0 + t], sum);
    }
}

// ---------------------------------------------------------------------------
// Per-token: LN1 -> router -> top2+softmax -> scatter; store LN2-normalized
// token as bf16 (eg/eb folded into weights); record slots per token.
// ---------------------------------------------------------------------------
__global__ __launch_bounds__(256) void token_kernel(
    const float* __restrict__ x, const float* __restrict__ lng, const float* __restrict__ lnb,
    const float* __restrict__ rw, __hip_bfloat16* __restrict__ xhat,
    int* __restrict__ counts, int* __restrict__ lists, float* __restrict__ gates,
    int* __restrict__ pairIdx)
{
    const int i = blockIdx.x;
    const int t = threadIdx.x;
    __shared__ float sA[256], sB[256];
    __shared__ float slog[32];

    float4 xv = ((const float4*)(x + (size_t)i * DD))[t];
    float s1 = xv.x + xv.y + xv.z + xv.w;
    float s2 = xv.x * xv.x + xv.y * xv.y + xv.z * xv.z + xv.w * xv.w;
    sA[t] = s1; sB[t] = s2;
    __syncthreads();
    for (int s = 128; s > 0; s >>= 1) {
        if (t < s) { sA[t] += sA[t + s]; sB[t] += sB[t + s]; }
        __syncthreads();
    }
    const float mu  = sA[0] * (1.0f / DD);
    const float var = sB[0] * (1.0f / DD) - mu * mu;
    const float rstd = rsqrtf(var + 1e-5f);
    __syncthreads();

    float4 gv = ((const float4*)lng)[t];
    float4 bv = ((const float4*)lnb)[t];
    float xf[4];
    xf[0] = (xv.x - mu) * rstd * gv.x + bv.x;
    xf[1] = (xv.y - mu) * rstd * gv.y + bv.y;
    xf[2] = (xv.z - mu) * rstd * gv.z + bv.z;
    xf[3] = (xv.w - mu) * rstd * gv.w + bv.w;

    float lp[8];
    #pragma unroll
    for (int e = 0; e < 8; e++) lp[e] = 0.f;
    {
        const float4* r4 = (const float4*)(rw + (size_t)(t * 4) * EE);
        #pragma unroll
        for (int j = 0; j < 4; j++) {
            float4 ra = r4[j * 2], rb = r4[j * 2 + 1];
            lp[0] += xf[j] * ra.x; lp[1] += xf[j] * ra.y;
            lp[2] += xf[j] * ra.z; lp[3] += xf[j] * ra.w;
            lp[4] += xf[j] * rb.x; lp[5] += xf[j] * rb.y;
            lp[6] += xf[j] * rb.z; lp[7] += xf[j] * rb.w;
        }
    }
    const int lane = t & 63, wid = t >> 6;
    #pragma unroll
    for (int e = 0; e < 8; e++) {
        float v = lp[e];
        #pragma unroll
        for (int o = 32; o > 0; o >>= 1) v += __shfl_down(v, o, 64);
        if (lane == 0) slog[e * 4 + wid] = v;
    }

    s1 = xf[0] + xf[1] + xf[2] + xf[3];
    s2 = xf[0] * xf[0] + xf[1] * xf[1] + xf[2] * xf[2] + xf[3] * xf[3];
    sA[t] = s1; sB[t] = s2;
    __syncthreads();
    for (int s = 128; s > 0; s >>= 1) {
        if (t < s) { sA[t] += sA[t + s]; sB[t] += sB[t + s]; }
        __syncthreads();
    }
    const float mu2  = sA[0] * (1.0f / DD);
    const float var2 = sB[0] * (1.0f / DD) - mu2 * mu2;
    const float rstd2 = rsqrtf(var2 + 1e-5f);

    union { ushort4 v; __hip_bfloat16 h[4]; } u;
    u.h[0] = __float2bfloat16((xf[0] - mu2) * rstd2);
    u.h[1] = __float2bfloat16((xf[1] - mu2) * rstd2);
    u.h[2] = __float2bfloat16((xf[2] - mu2) * rstd2);
    u.h[3] = __float2bfloat16((xf[3] - mu2) * rstd2);
    ((ushort4*)(xhat + (size_t)i * DD))[t] = u.v;

    if (t == 0) {
        float lg[8];
        #pragma unroll
        for (int e = 0; e < 8; e++)
            lg[e] = slog[e * 4] + slog[e * 4 + 1] + slog[e * 4 + 2] + slog[e * 4 + 3];
        int i0 = 0;
        #pragma unroll
        for (int e = 1; e < 8; e++) if (lg[e] > lg[i0]) i0 = e;
        int i1 = (i0 == 0) ? 1 : 0;
        #pragma unroll
        for (int e = 0; e < 8; e++) { if (e != i0 && lg[e] > lg[i1]) i1 = e; }
        const float ex = __expf(lg[i1] - lg[i0]);
        const float g0 = 1.f / (1.f + ex);
        const float g1 = ex / (1.f + ex);
        int p0 = atomicAdd(&counts[i0], 1);
        lists[i0 * NN + p0] = i; gates[i0 * NN + p0] = g0;
        int p1 = atomicAdd(&counts[i1], 1);
        lists[i1 * NN + p1] = i; gates[i1 * NN + p1] = g1;
        pairIdx[2 * i]     = i0 * NN + p0;
        pairIdx[2 * i + 1] = i1 * NN + p1;
    }
}

// ---------------------------------------------------------------------------
// GEMM1 v8: R7 geometry (4 waves, BM=128, BK=32, 128 h-cols x {W1,W2},
// 48KB LDS, 2+ blocks/CU) with the K-loop FULLY UNROLLED: every stage/ds_read
// address becomes base-VGPR + immediate offset (compiler folds const adds,
// m254) -> per-K-step VALU addr arithmetic eliminated.
// ---------------------------------------------------------------------------
__global__ __launch_bounds__(256, 2) void gemm1_kernel(
    const __hip_bfloat16* __restrict__ xhat,
    const __hip_bfloat16* __restrict__ w1t, const __hip_bfloat16* __restrict__ w2t,
    const float* __restrict__ b1, const float* __restrict__ b2,
    const float* __restrict__ b1a, const float* __restrict__ b2a,
    const int* __restrict__ counts, const int* __restrict__ lists,
    __hip_bfloat16* __restrict__ hid)
{
    const int gid  = blockIdx.x;            // 0..4095
    const int xcd  = gid & 7;
    const int rest = gid >> 3;              // 0..511
    const int m    = rest & 15;
    const int pidx = rest >> 4;             // 0..31
    const int panel = xcd + 8 * pidx;       // 0..255: all m-blocks of panel on one XCD
    const int e   = panel >> 5;
    const int h0  = (panel & 31) * 128;
    const int cnt = counts[e];
    const int m0  = m * 128;
    if (m0 >= cnt) return;
    int base = 0;
    #pragma unroll
    for (int j = 0; j < 8; j++) base += (j < e) ? counts[j] : 0;

    __shared__ __align__(16) __hip_bfloat16 As[2][128 * 32];   // 8KB x2
    __shared__ __align__(16) __hip_bfloat16 Bs[2][256 * 32];   // 16KB x2: rows 0-127 W1, 128-255 W2
    __shared__ int toks[128];

    const int t = threadIdx.x, lane = t & 63, w = t >> 6;   // w = wn 0..3
    const int rsel = lane & 15, crd = lane >> 4;
    const int lr = lane >> 2;                               // staging row-in-16
    const int cl = (lane & 3) ^ ((lane >> 3) & 3);          // inverse-swizzled src chunk
    const int koff = (crd ^ ((rsel >> 1) & 3)) * 8;         // frag-read chunk

    if (t < 128) toks[t] = lists[e * NN + min(m0 + t, cnt - 1)];

    f32x4 acc1[8][2], acc2[8][2];
    const f32x4 z4 = {0.f, 0.f, 0.f, 0.f};
    #pragma unroll
    for (int q = 0; q < 8; q++) {
        acc1[q][0] = z4; acc1[q][1] = z4;
        acc2[q][0] = z4; acc2[q][1] = z4;
    }

    __syncthreads();                        // toks visible

    const __hip_bfloat16* pA[2];
    #pragma unroll
    for (int i = 0; i < 2; i++)
        pA[i] = xhat + (size_t)toks[w * 32 + i * 16 + lr] * DD + cl * 8;
    const __hip_bfloat16* pB[4];
    {
        const __hip_bfloat16* wsel = (w < 2) ? w1t : w2t;
        #pragma unroll
        for (int i = 0; i < 4; i++) {
            const int brow = (w & 1) * 64 + i * 16 + lr;    // row within matrix
            pB[i] = wsel + ((size_t)e * HH + h0 + brow) * DD + cl * 8;
        }
    }

    auto STAGE = [&](int buf, int ko) {
        #pragma unroll
        for (int i = 0; i < 2; i++)
            __builtin_amdgcn_global_load_lds(AS1P(pA[i] + ko), AS3P(&As[buf][w * 1024 + i * 512]), 16, 0, 0);
        #pragma unroll
        for (int i = 0; i < 4; i++)
            __builtin_amdgcn_global_load_lds(AS1P(pB[i] + ko), AS3P(&Bs[buf][w * 2048 + i * 512]), 16, 0, 0);
    };
    auto COMPUTE = [&](int buf) {
        bf16x8 af[8], b1q[2], b2q[2];
        #pragma unroll
        for (int mi = 0; mi < 8; mi++)
            af[mi] = *(const bf16x8*)&As[buf][(mi * 16 + rsel) * 32 + koff];
        #pragma unroll
        for (int ni = 0; ni < 2; ni++) {
            b1q[ni] = *(const bf16x8*)&Bs[buf][(w * 32 + ni * 16 + rsel) * 32 + koff];
            b2q[ni] = *(const bf16x8*)&Bs[buf][(4096 + (w * 32 + ni * 16 + rsel) * 32) + koff];
        }
        __builtin_amdgcn_s_setprio(1);
        #pragma unroll
        for (int mi = 0; mi < 8; mi++)
            #pragma unroll
            for (int ni = 0; ni < 2; ni++) {
                acc1[mi][ni] = mfma16(af[mi], b1q[ni], acc1[mi][ni]);
                acc2[mi][ni] = mfma16(af[mi], b2q[ni], acc2[mi][ni]);
            }
        __builtin_amdgcn_s_setprio(0);
    };

    STAGE(0, 0);
    __syncthreads();
    #pragma unroll
    for (int it = 0; it < 15; ++it) {
        STAGE(1, it * 64 + 32); COMPUTE(0); __syncthreads();
        STAGE(0, it * 64 + 64); COMPUTE(1); __syncthreads();
    }
    STAGE(1, 992); COMPUTE(0); __syncthreads();
    COMPUTE(1);

    const int rq = (lane >> 4) * 4, cq = lane & 15;
    #pragma unroll
    for (int ni = 0; ni < 2; ni++) {
        const int hcol = h0 + w * 32 + ni * 16 + cq;
        const float bb1 = b1[e * HH + hcol] + b1a[e * HH + hcol];
        const float bb2 = b2[e * HH + hcol] + b2a[e * HH + hcol];
        #pragma unroll
        for (int mi = 0; mi < 8; mi++) {
            f32x4 v1 = acc1[mi][ni];
            f32x4 v2 = acc2[mi][ni];
            #pragma unroll
            for (int r = 0; r < 4; r++) {
                const int pos = m0 + mi * 16 + rq + r;
                if (pos < cnt) {
                    float x1 = v1[r] + bb1;
                    float x2 = v2[r] + bb2;
                    x2 = fminf(fmaxf(x2, -20.f), 20.f);
                    float hv = x1 * (x2 / (1.f + __expf(-x2)));
                    hv = fminf(fmaxf(hv, -1e4f), 1e4f);
                    hid[(size_t)(base + pos) * HH + hcol] = __float2bfloat16(hv);
                }
            }
        }
    }
}

// ---------------------------------------------------------------------------
// GEMM2 v8: 4 waves, BM=128, BN=256 d-cols, BK=32, split-K=4 (K=1024/block),
// fully unrolled like gemm1. Raw partials to P0..P3; bias/clip/gate in combine.
// ---------------------------------------------------------------------------
__global__ __launch_bounds__(256, 2) void gemm2_kernel(
    const __hip_bfloat16* __restrict__ hid, const __hip_bfloat16* __restrict__ wot,
    const int* __restrict__ counts, float* __restrict__ P0, float* __restrict__ P1,
    float* __restrict__ P2, float* __restrict__ P3)
{
    const int gid  = blockIdx.x;            // 0..2047
    const int xcd  = gid & 7;
    const int rest = gid >> 3;              // 0..255
    const int m    = rest & 15;
    const int q    = rest >> 4;             // 0..15
    const int sp   = q & 3;
    const int pidx = q >> 2;                // 0..3
    const int panel = xcd + 8 * pidx;       // 0..31
    const int e   = panel >> 2;
    const int d0  = (panel & 3) * 256;
    const int cnt = counts[e];
    const int m0  = m * 128;
    if (m0 >= cnt) return;
    int base = 0;
    #pragma unroll
    for (int j = 0; j < 8; j++) base += (j < e) ? counts[j] : 0;

    __shared__ __align__(16) __hip_bfloat16 As[2][128 * 32];
    __shared__ __align__(16) __hip_bfloat16 Bs[2][256 * 32];

    const int t = threadIdx.x, lane = t & 63, w = t >> 6;
    const int rsel = lane & 15, crd = lane >> 4;
    const int lr = lane >> 2;
    const int cl = (lane & 3) ^ ((lane >> 3) & 3);
    const int koff = (crd ^ ((rsel >> 1) & 3)) * 8;

    f32x4 acc[8][4];
    const f32x4 z4 = {0.f, 0.f, 0.f, 0.f};
    #pragma unroll
    for (int qq = 0; qq < 8; qq++) {
        acc[qq][0] = z4; acc[qq][1] = z4; acc[qq][2] = z4; acc[qq][3] = z4;
    }

    const int kbase = sp * 1024;
    const __hip_bfloat16* pA[2];
    #pragma unroll
    for (int i = 0; i < 2; i++)
        pA[i] = hid + (size_t)(base + min(m0 + w * 32 + i * 16 + lr, cnt - 1)) * HH + kbase + cl * 8;
    const __hip_bfloat16* pB[4];
    #pragma unroll
    for (int i = 0; i < 4; i++)
        pB[i] = wot + ((size_t)e * DD + d0 + w * 64 + i * 16 + lr) * HH + kbase + cl * 8;

    auto STAGE = [&](int buf, int ko) {
        #pragma unroll
        for (int i = 0; i < 2; i++)
            __builtin_amdgcn_global_load_lds(AS1P(pA[i] + ko), AS3P(&As[buf][w * 1024 + i * 512]), 16, 0, 0);
        #pragma unroll
        for (int i = 0; i < 4; i++)
            __builtin_amdgcn_global_load_lds(AS1P(pB[i] + ko), AS3P(&Bs[buf][w * 2048 + i * 512]), 16, 0, 0);
    };
    auto COMPUTE = [&](int buf) {
        bf16x8 af[8], bq[4];
        #pragma unroll
        for (int mi = 0; mi < 8; mi++)
            af[mi] = *(const bf16x8*)&As[buf][(mi * 16 + rsel) * 32 + koff];
        #pragma unroll
        for (int ni = 0; ni < 4; ni++)
            bq[ni] = *(const bf16x8*)&Bs[buf][(w * 64 + ni * 16 + rsel) * 32 + koff];
        __builtin_amdgcn_s_setprio(1);
        #pragma unroll
        for (int mi = 0; mi < 8; mi++)
            #pragma unroll
            for (int ni = 0; ni < 4; ni++)
                acc[mi][ni] = mfma16(af[mi], bq[ni], acc[mi][ni]);
        __builtin_amdgcn_s_setprio(0);
    };

    STAGE(0, 0);
    __syncthreads();
    #pragma unroll
    for (int it = 0; it < 15; ++it) {
        STAGE(1, it * 64 + 32); COMPUTE(0); __syncthreads();
        STAGE(0, it * 64 + 64); COMPUTE(1); __syncthreads();
    }
    STAGE(1, 992); COMPUTE(0); __syncthreads();
    COMPUTE(1);

    float* dst = (sp == 0) ? P0 : (sp == 1) ? P1 : (sp == 2) ? P2 : P3;
    const int rq = (lane >> 4) * 4, cq = lane & 15;
    #pragma unroll
    for (int ni = 0; ni < 4; ni++) {
        const int dcol = d0 + w * 64 + ni * 16 + cq;
        #pragma unroll
        for (int mi = 0; mi < 8; mi++) {
            f32x4 v = acc[mi][ni];
            #pragma unroll
            for (int r = 0; r < 4; r++) {
                const int pos = m0 + mi * 16 + rq + r;
                if (pos < cnt)
                    dst[(size_t)(base + pos) * DD + dcol] = v[r];
            }
        }
    }
}

// ---------------------------------------------------------------------------
// Combine: out[token] = sum_slots gate * clip(P0+P1+P2+P3 + bo[e], +-1e4)
// ---------------------------------------------------------------------------
__global__ __launch_bounds__(256) void combine_kernel(
    const float* __restrict__ P0, const float* __restrict__ P1,
    const float* __restrict__ P2, const float* __restrict__ P3,
    const float* __restrict__ bo, const int* __restrict__ counts,
    const int* __restrict__ pairIdx, const float* __restrict__ gates,
    float* __restrict__ out)
{
    const int i = blockIdx.x;
    const int t = threadIdx.x;
    const int s0 = pairIdx[2 * i], s1 = pairIdx[2 * i + 1];
    const int e0 = s0 >> 12, p0 = s0 & (NN - 1);
    const int e1 = s1 >> 12, p1 = s1 & (NN - 1);
    int b0 = 0, b1 = 0;
    #pragma unroll
    for (int j = 0; j < 8; j++) {
        const int c = counts[j];
        b0 += (j < e0) ? c : 0;
        b1 += (j < e1) ? c : 0;
    }
    const float g0 = gates[s0], g1 = gates[s1];
    const size_t r0 = (size_t)(b0 + p0) * DD + t * 4;
    const size_t r1 = (size_t)(b1 + p1) * DD + t * 4;
    const float4 a00 = *(const float4*)(P0 + r0), a01 = *(const float4*)(P1 + r0);
    const float4 a02 = *(const float4*)(P2 + r0), a03 = *(const float4*)(P3 + r0);
    const float4 a10 = *(const float4*)(P0 + r1), a11 = *(const float4*)(P1 + r1);
    const float4 a12 = *(const float4*)(P2 + r1), a13 = *(const float4*)(P3 + r1);
    const float4 q0 = ((const float4*)(bo + (size_t)e0 * DD))[t];
    const float4 q1 = ((const float4*)(bo + (size_t)e1 * DD))[t];
    float4 r;
    #pragma unroll
    for (int k = 0; k < 4; k++) {
        float v0 = ((const float*)&a00)[k] + ((const float*)&a01)[k]
                 + ((const float*)&a02)[k] + ((const float*)&a03)[k] + ((const float*)&q0)[k];
        float v1 = ((const float*)&a10)[k] + ((const float*)&a11)[k]
                 + ((const float*)&a12)[k] + ((const float*)&a13)[k] + ((const float*)&q1)[k];
        v0 = fminf(fmaxf(v0, -1e4f), 1e4f);
        v1 = fminf(fmaxf(v1, -1e4f), 1e4f);
        ((float*)&r)[k] = g0 * v0 + g1 * v1;
    }
    ((float4*)(out + (size_t)i * DD))[t] = r;
}

// ---------------------------------------------------------------------------
extern "C" void kernel_launch(void* const* d_in, const int* in_sizes, int n_in,
                              void* d_out, int out_size, void* d_ws, size_t ws_size,
                              hipStream_t stream)
{
    const float* x   = (const float*)d_in[0];
    const float* lng = (const float*)d_in[1];
    const float* lnb = (const float*)d_in[2];
    const float* rw  = (const float*)d_in[3];
    const float* eg  = (const float*)d_in[4];
    const float* eb  = (const float*)d_in[5];
    const float* W1  = (const float*)d_in[6];
    const float* b1  = (const float*)d_in[7];
    const float* W2  = (const float*)d_in[8];
    const float* b2  = (const float*)d_in[9];
    const float* Wo  = (const float*)d_in[10];
    const float* bo  = (const float*)d_in[11];
    float* out = (float*)d_out;

    char* ws = (char*)d_ws;
    const size_t WSZ = (size_t)EE * HH * DD * 2;      // 64MB per weight matrix
    __hip_bfloat16* W1T  = (__hip_bfloat16*)(ws);
    __hip_bfloat16* W2T  = (__hip_bfloat16*)(ws + WSZ);
    __hip_bfloat16* WoT  = (__hip_bfloat16*)(ws + 2 * WSZ);
    __hip_bfloat16* xhat = (__hip_bfloat16*)(ws + 3 * WSZ);
    __hip_bfloat16* hid  = (__hip_bfloat16*)(ws + 3 * WSZ + (size_t)NN * DD * 2);
    char* small = ws + 3 * WSZ + (size_t)NN * DD * 2 + (size_t)2 * NN * HH * 2;
    int*   counts  = (int*)small;
    float* b1a     = (float*)(small + 256);
    float* b2a     = (float*)(small + 256 + 131072);
    int*   lists   = (int*)(small + 256 + 2 * 131072);
    float* gates   = (float*)(small + 256 + 3 * 131072);
    int*   pairIdx = (int*)(small + 256 + 4 * 131072);
    // split-K partials (each 8192x1024 f32 = 32MB): P0/P1 alias W1T, P2/P3 alias
    // W2T — both dead after gemm1, rewritten by transpose_all next call.
    float* P0 = (float*)(ws);
    float* P1 = (float*)(ws + WSZ / 2);
    float* P2 = (float*)(ws + WSZ);
    float* P3 = (float*)(ws + WSZ + WSZ / 2);

    hipMemsetAsync(small, 0, 256 + 2 * 131072, stream);   // counts + b1a + b2a

    transpose_all<<<dim3(1024, 1, 24), 256, 0, stream>>>(
        W1, W2, Wo, eg, eb, W1T, W2T, WoT, b1a, b2a);

    token_kernel<<<NN, 256, 0, stream>>>(x, lng, lnb, rw, xhat, counts, lists, gates, pairIdx);

    gemm1_kernel<<<4096, 256, 0, stream>>>(
        xhat, W1T, W2T, b1, b2, b1a, b2a, counts, lists, hid);
    gemm2_kernel<<<2048, 256, 0, stream>>>(
        hid, WoT, counts, P0, P1, P2, P3);
    combine_kernel<<<NN, 256, 0, stream>>>(P0, P1, P2, P3, bo, counts, pairIdx, gates, out);
}